// Round 8
// baseline (84.650 us; speedup 1.0000x reference)
//
#include <hip/hip_runtime.h>
#include <math.h>

#define N 512
#define SIGMA 0.5f
#define EPS 1e-7f

typedef __attribute__((ext_vector_type(8))) short bf16x8;
typedef __attribute__((ext_vector_type(4))) float f32x4;

__device__ __forceinline__ unsigned short f2bf(float x) {
    unsigned int b = __float_as_uint(x);
    b += 0x7FFFu + ((b >> 16) & 1u);   // RNE; inputs finite
    return (unsigned short)(b >> 16);
}
__device__ __forceinline__ float bf2f(unsigned short h) {
    return __uint_as_float((unsigned int)h << 16);
}

// ---------------------------------------------------------------------------
// Kernel 1: grid 520 x 64.
//  blocks 0..511  : fp32->bf16 convert + sq-norms (R7 verbatim)
//  blocks 512..519: label rank-sort, 1 thread per label (64 labels/block).
//    Exact stable rank; outputs sl (sorted labels), sidx (sorted->orig),
//    ipos (orig->sorted). Runs concurrent with convert — no serial tail.
// ---------------------------------------------------------------------------
__global__ void convert_kernel(const float* __restrict__ feat,
                               const float* __restrict__ label,
                               unsigned short* __restrict__ featb,
                               float* __restrict__ sqn,
                               float* __restrict__ sl,
                               int* __restrict__ sidx,
                               int* __restrict__ ipos,
                               float* __restrict__ out) {
    const int lane = threadIdx.x;            // 0..63
    if (blockIdx.x < 512) {
        const int row = blockIdx.x;
        if (row == 0 && lane == 0) out[0] = 0.f;
        const float* f = feat + (size_t)row * N;
        unsigned short* fb = featb + (size_t)row * N;
        float s = 0.f;
        #pragma unroll
        for (int sweep = 0; sweep < 2; ++sweep) {
            int c = sweep * 256 + lane * 4;
            float4 v = *(const float4*)(f + c);
            unsigned short b0 = f2bf(v.x), b1 = f2bf(v.y),
                           b2 = f2bf(v.z), b3 = f2bf(v.w);
            *(ushort4*)(fb + c) = make_ushort4(b0, b1, b2, b3);
            float r0 = bf2f(b0), r1 = bf2f(b1), r2 = bf2f(b2), r3 = bf2f(b3);
            s += r0 * r0 + r1 * r1 + r2 * r2 + r3 * r3;
        }
        #pragma unroll
        for (int off = 32; off > 0; off >>= 1) s += __shfl_down(s, off);
        if (lane == 0) sqn[row] = s;
    } else {
        __shared__ __align__(16) float lab[N];
        // stage all labels: 2 float4 per thread
        #pragma unroll
        for (int q = 0; q < 2; ++q)
            ((float4*)lab)[lane * 2 + q] = ((const float4*)label)[lane * 2 + q];
        __syncthreads();
        const int t = (blockIdx.x - 512) * 64 + lane;   // my label
        const float lt = lab[t];
        int rank = 0;
        const float4* L4 = (const float4*)lab;
        #pragma unroll 8
        for (int j4 = 0; j4 < N / 4; ++j4) {
            float4 v = L4[j4];
            int j = j4 * 4;
            rank += ((v.x < lt) || (v.x == lt && (j + 0) < t)) ? 1 : 0;
            rank += ((v.y < lt) || (v.y == lt && (j + 1) < t)) ? 1 : 0;
            rank += ((v.z < lt) || (v.z == lt && (j + 2) < t)) ? 1 : 0;
            rank += ((v.w < lt) || (v.w == lt && (j + 3) < t)) ? 1 : 0;
        }
        sl[rank] = lt;     // exact bits, permuted
        sidx[rank] = t;
        ipos[t] = rank;
    }
}

// ---------------------------------------------------------------------------
// Kernel 2 (R7 verbatim): symmetric F via bf16 MFMA, 528 lower-tri tiles,
// each written row-major + mirrored (float4 down-column store).
// ---------------------------------------------------------------------------
__global__ __launch_bounds__(64)
void fmat_sym_kernel(const unsigned short* __restrict__ featb,
                     const float* __restrict__ sqn,
                     float* __restrict__ Fm) {
    const int id = blockIdx.x;               // 0..527
    int bi = (int)((sqrtf(8.f * (float)id + 1.f) - 1.f) * 0.5f);
    while ((bi + 1) * (bi + 2) / 2 <= id) ++bi;
    while (bi * (bi + 1) / 2 > id) --bi;
    const int bj = id - bi * (bi + 1) / 2;   // bj <= bi

    const int r0 = bi * 16;
    const int c0 = bj * 16;
    const int lane = threadIdx.x;
    const int m = lane & 15;
    const int kb = (lane >> 4) * 8;

    const unsigned short* arow = featb + (size_t)(r0 + m) * N + kb;
    const unsigned short* brow = featb + (size_t)(c0 + m) * N + kb;

    f32x4 acc = {0.f, 0.f, 0.f, 0.f};
    #pragma unroll
    for (int k0 = 0; k0 < N; k0 += 32) {
        bf16x8 a = *(const bf16x8*)(arow + k0);
        bf16x8 b = *(const bf16x8*)(brow + k0);
        acc = __builtin_amdgcn_mfma_f32_16x16x32_bf16(a, b, acc, 0, 0, 0);
    }

    // D-layout (HW-validated): col = lane&15, row = (lane>>4)*4 + reg
    const int col = c0 + m;
    const int rowb = r0 + (lane >> 4) * 4;
    const float nc = sqn[col];
    float v0_, v1_, v2_, v3_;
    #pragma unroll
    for (int r = 0; r < 4; ++r) {
        const int row = rowb + r;
        float sq = sqn[row] + nc - 2.f * acc[r];
        float v = (row == col) ? 0.f : -SIGMA * sqrtf(fmaxf(sq, 0.f));
        Fm[(size_t)row * N + col] = v;
        if (r == 0) v0_ = v; else if (r == 1) v1_ = v;
        else if (r == 2) v2_ = v; else v3_ = v;
    }
    *(float4*)(Fm + (size_t)col * N + rowb) = make_float4(v0_, v1_, v2_, v3_);
}

// ---------------------------------------------------------------------------
// Kernel 3: per-row softmax + sorted-interval denom + loss.
// Thread t serves sorted position p=t (ds_, scan) AND original column k=t.
// denom[k] = total - sum_{p in [La,Rb]} Ssorted[p]; the inner set
// {p : d[p] < Rk} is a contiguous interval around posi because d is
// V-shaped (exact fp, monotone per half). Two 9-probe binary searches
// replace the 512-iteration brute loop. S[i]=0 is zeroed BEFORE the scan,
// so total ~ 5e-5 and scan abs error ~1e-10 << denom_min ~1e-7 (R3
// empirically confirmed absmax 0.0 with this arithmetic).
// ---------------------------------------------------------------------------
__global__ __launch_bounds__(512, 4)
void row_kernel(const float* __restrict__ Fm,
                const float* __restrict__ label,
                const float* __restrict__ sl,
                const int* __restrict__ sidx,
                const int* __restrict__ ipos,
                float* __restrict__ out) {
    const int i = blockIdx.x;
    const int t = threadIdx.x;        // 0..511
    const int wave = t >> 6, lane = t & 63;

    __shared__ __align__(16) float ds_[N];  // distance at sorted position
    __shared__ __align__(16) float Ss[N];   // S by orig column
    __shared__ __align__(16) float Ps[N];   // inclusive prefix of sorted S
    __shared__ float red[8];
    __shared__ float wsum[8];

    const float li = label[i];
    const float f = Fm[(size_t)i * N + t];
    const float e = __expf(f);        // row max exactly 0 -> no max pass

    ds_[t] = fabsf(li - sl[t]);       // bitwise == reference R values

    // Z = sum_j exp(f_j) (includes diagonal, exp(0)=1)
    float z = e;
    #pragma unroll
    for (int off = 32; off > 0; off >>= 1) z += __shfl_xor(z, off);
    if (lane == 0) red[wave] = z;
    __syncthreads();
    const float Z = red[0] + red[1] + red[2] + red[3] +
                    red[4] + red[5] + red[6] + red[7];
    float S = e / Z;
    if (t == i) S = 0.f;              // exclude j==i from all denom sums
    Ss[t] = S;
    __syncthreads();

    // gather into sorted order + block-wide inclusive scan
    float v = Ss[sidx[t]];
    #pragma unroll
    for (int off = 1; off < 64; off <<= 1) {
        float u = __shfl_up(v, off);
        if (lane >= off) v += u;
    }
    if (lane == 63) wsum[wave] = v;
    __syncthreads();
    float base = 0.f;
    #pragma unroll
    for (int w = 0; w < 8; ++w) base += (w < wave) ? wsum[w] : 0.f;
    Ps[t] = base + v;
    __syncthreads();

    const float total = Ps[N - 1];
    const int posi = ipos[i];         // uniform scalar
    const float Rk = fabsf(li - label[t]);  // == ds_[ipos[t]] bitwise

    // left half [0, posi], d non-increasing: first p with d[p] < Rk
    int lo = 0, hi = posi + 1;
    while (lo < hi) { int mid = (lo + hi) >> 1; if (ds_[mid] < Rk) hi = mid; else lo = mid + 1; }
    const int La = lo;
    // right half [posi, N), d non-decreasing: first p with d[p] >= Rk
    lo = posi; hi = N;
    while (lo < hi) { int mid = (lo + hi) >> 1; if (ds_[mid] >= Rk) hi = mid; else lo = mid + 1; }
    const int Rb = lo - 1;            // last p with d < Rk

    const float inner = ((Rb >= 0) ? Ps[Rb] : 0.f) - ((La > 0) ? Ps[La - 1] : 0.f);
    const float denom = total - inner;
    float part = (t == i) ? 0.f : (f - __logf(denom + EPS));

    #pragma unroll
    for (int off = 32; off > 0; off >>= 1) part += __shfl_xor(part, off);
    if (lane == 0) red[wave] = part;
    __syncthreads();
    if (t == 0) {
        float tot = red[0] + red[1] + red[2] + red[3] +
                    red[4] + red[5] + red[6] + red[7];
        atomicAdd(out, tot * (-1.f / ((float)N * (float)(N - 1))));
    }
}

// ---------------------------------------------------------------------------
extern "C" void kernel_launch(void* const* d_in, const int* in_sizes, int n_in,
                              void* d_out, int out_size, void* d_ws, size_t ws_size,
                              hipStream_t stream) {
    const float* feature = (const float*)d_in[0];   // [512, 512] f32
    const float* label   = (const float*)d_in[1];   // [512, 1]  f32
    float* out = (float*)d_out;

    float* Fm             = (float*)d_ws;                          // 1 MB
    unsigned short* featb = (unsigned short*)(Fm + (size_t)N * N); // 512 KB
    float* sqn            = (float*)(featb + (size_t)N * N);       // 2 KB
    float* sl             = sqn + N;                               // 2 KB
    int*   sidx           = (int*)(sl + N);                        // 2 KB
    int*   ipos           = sidx + N;                              // 2 KB

    convert_kernel<<<520, 64, 0, stream>>>(feature, label, featb, sqn,
                                           sl, sidx, ipos, out);
    fmat_sym_kernel<<<528, 64, 0, stream>>>(featb, sqn, Fm);
    row_kernel<<<N, N, 0, stream>>>(Fm, label, sl, sidx, ipos, out);
}

// Round 9
// 77.430 us; speedup vs baseline: 1.0932x; 1.0932x over previous
//
#include <hip/hip_runtime.h>
#include <math.h>

#define N 512
#define SIGMA 0.5f
#define EPS 1e-7f

typedef __attribute__((ext_vector_type(8))) short bf16x8;
typedef __attribute__((ext_vector_type(4))) float f32x4;

__device__ __forceinline__ unsigned short f2bf(float x) {
    unsigned int b = __float_as_uint(x);
    b += 0x7FFFu + ((b >> 16) & 1u);   // RNE; inputs finite
    return (unsigned short)(b >> 16);
}
__device__ __forceinline__ float bf2f(unsigned short h) {
    return __uint_as_float((unsigned int)h << 16);
}

// ---------------------------------------------------------------------------
// Kernel 1: fp32 -> bf16 convert + sq-norms of rounded values.
// One wave per row; also zeroes the loss accumulator.
// ---------------------------------------------------------------------------
__global__ void convert_kernel(const float* __restrict__ feat,
                               unsigned short* __restrict__ featb,
                               float* __restrict__ sqn,
                               float* __restrict__ out) {
    const int row = blockIdx.x;
    const int lane = threadIdx.x;            // 0..63
    if (row == 0 && lane == 0) out[0] = 0.f; // zero loss accumulator

    const float* f = feat + (size_t)row * N;
    unsigned short* fb = featb + (size_t)row * N;
    float s = 0.f;
    #pragma unroll
    for (int sweep = 0; sweep < 2; ++sweep) {
        int c = sweep * 256 + lane * 4;
        float4 v = *(const float4*)(f + c);
        unsigned short b0 = f2bf(v.x), b1 = f2bf(v.y),
                       b2 = f2bf(v.z), b3 = f2bf(v.w);
        *(ushort4*)(fb + c) = make_ushort4(b0, b1, b2, b3);
        float r0 = bf2f(b0), r1 = bf2f(b1), r2 = bf2f(b2), r3 = bf2f(b3);
        s += r0 * r0 + r1 * r1 + r2 * r2 + r3 * r3;
    }
    #pragma unroll
    for (int off = 32; off > 0; off >>= 1) s += __shfl_down(s, off);
    if (lane == 0) sqn[row] = s;
}

// ---------------------------------------------------------------------------
// Kernel 2: symmetric F via bf16 MFMA. 528 blocks = lower-triangle 16x16
// tiles (bi >= bj). Each wave computes one tile and writes it twice:
//  - row-major scalar stores (coalesced)
//  - transposed float4 store: acc[0..3] are 4 consecutive ROWS at one col,
//    contiguous at Fm[col*N + rowb] (16B aligned).
// Diagonal tiles double-write identical values (benign).
// ---------------------------------------------------------------------------
__global__ __launch_bounds__(64)
void fmat_sym_kernel(const unsigned short* __restrict__ featb,
                     const float* __restrict__ sqn,
                     float* __restrict__ Fm) {
    const int id = blockIdx.x;               // 0..527
    // triangular decode: bi = largest with bi*(bi+1)/2 <= id
    int bi = (int)((sqrtf(8.f * (float)id + 1.f) - 1.f) * 0.5f);
    while ((bi + 1) * (bi + 2) / 2 <= id) ++bi;
    while (bi * (bi + 1) / 2 > id) --bi;
    const int bj = id - bi * (bi + 1) / 2;   // bj <= bi

    const int r0 = bi * 16;
    const int c0 = bj * 16;
    const int lane = threadIdx.x;
    const int m = lane & 15;
    const int kb = (lane >> 4) * 8;

    const unsigned short* arow = featb + (size_t)(r0 + m) * N + kb;
    const unsigned short* brow = featb + (size_t)(c0 + m) * N + kb;

    f32x4 acc = {0.f, 0.f, 0.f, 0.f};
    #pragma unroll
    for (int k0 = 0; k0 < N; k0 += 32) {
        bf16x8 a = *(const bf16x8*)(arow + k0);
        bf16x8 b = *(const bf16x8*)(brow + k0);
        acc = __builtin_amdgcn_mfma_f32_16x16x32_bf16(a, b, acc, 0, 0, 0);
    }

    // D-layout (HW-validated rounds 2-7): col = lane&15, row = (lane>>4)*4+reg
    const int col = c0 + m;
    const int rowb = r0 + (lane >> 4) * 4;
    const float nc = sqn[col];
    float v0_, v1_, v2_, v3_;
    #pragma unroll
    for (int r = 0; r < 4; ++r) {
        const int row = rowb + r;
        float sq = sqn[row] + nc - 2.f * acc[r];
        float v = (row == col) ? 0.f : -SIGMA * sqrtf(fmaxf(sq, 0.f));
        Fm[(size_t)row * N + col] = v;
        if (r == 0) v0_ = v; else if (r == 1) v1_ = v;
        else if (r == 2) v2_ = v; else v3_ = v;
    }
    // mirror: F[col][rowb..rowb+3] contiguous, 16B-aligned
    *(float4*)(Fm + (size_t)col * N + rowb) = make_float4(v0_, v1_, v2_, v3_);
}

// ---------------------------------------------------------------------------
// Kernel 3: per-row softmax + brute denom + loss (best measured: the
// float4-broadcast loop is throughput-bound and beats scan+search twice).
// One block (512 threads) per row i; thread t owns column t.
// Row max is exactly 0 (diag F = 0, off-diag < 0) -> no max pass.
// ---------------------------------------------------------------------------
__global__ __launch_bounds__(512, 4)
void row_kernel(const float* __restrict__ Fm,
                const float* __restrict__ label,
                float* __restrict__ out) {
    const int i = blockIdx.x;
    const int t = threadIdx.x;   // 0..511
    const int wave = t >> 6, lane = t & 63;

    __shared__ __align__(16) float Rs[N];
    __shared__ __align__(16) float Ss[N];
    __shared__ float red[8];

    const float li = label[i];
    const float f = Fm[(size_t)i * N + t];
    const float Rk = fabsf(li - label[t]);
    Rs[t] = Rk;

    const float e = __expf(f);

    // Z = sum_j exp(f_j) (includes diagonal, exp(0)=1)
    float s = e;
    #pragma unroll
    for (int off = 32; off > 0; off >>= 1) s += __shfl_xor(s, off);
    if (lane == 0) red[wave] = s;
    __syncthreads();
    const float Z = red[0] + red[1] + red[2] + red[3] +
                    red[4] + red[5] + red[6] + red[7];

    float S = e / Z;
    if (t == i) S = 0.f;         // exclude j==i from all denom sums
    Ss[t] = S;
    __syncthreads();

    // denom[k=t] = sum_j [R[j] >= R[k]] * S[j], float4 LDS broadcasts
    float denom = 0.f;
    const float4* R4 = (const float4*)Rs;
    const float4* S4 = (const float4*)Ss;
    #pragma unroll 16
    for (int j4 = 0; j4 < N / 4; ++j4) {
        float4 r = R4[j4];
        float4 sv = S4[j4];
        denom += (r.x >= Rk) ? sv.x : 0.f;
        denom += (r.y >= Rk) ? sv.y : 0.f;
        denom += (r.z >= Rk) ? sv.z : 0.f;
        denom += (r.w >= Rk) ? sv.w : 0.f;
    }

    float part = (t == i) ? 0.f : (f - __logf(denom + EPS));

    #pragma unroll
    for (int off = 32; off > 0; off >>= 1) part += __shfl_xor(part, off);
    if (lane == 0) red[wave] = part;
    __syncthreads();
    if (t == 0) {
        float tot = red[0] + red[1] + red[2] + red[3] +
                    red[4] + red[5] + red[6] + red[7];
        atomicAdd(out, tot * (-1.f / ((float)N * (float)(N - 1))));
    }
}

// ---------------------------------------------------------------------------
extern "C" void kernel_launch(void* const* d_in, const int* in_sizes, int n_in,
                              void* d_out, int out_size, void* d_ws, size_t ws_size,
                              hipStream_t stream) {
    const float* feature = (const float*)d_in[0];   // [512, 512] f32
    const float* label   = (const float*)d_in[1];   // [512, 1]  f32
    float* out = (float*)d_out;

    float* Fm             = (float*)d_ws;                          // 1 MB
    unsigned short* featb = (unsigned short*)(Fm + (size_t)N * N); // 512 KB
    float* sqn            = (float*)(featb + (size_t)N * N);       // 2 KB

    convert_kernel<<<N, 64, 0, stream>>>(feature, featb, sqn, out);
    fmat_sym_kernel<<<528, 64, 0, stream>>>(featb, sqn, Fm);
    row_kernel<<<N, N, 0, stream>>>(Fm, label, out);
}